// Round 15
// baseline (689.453 us; speedup 1.0000x reference)
//
#include <hip/hip_runtime.h>
#include <hip/hip_fp16.h>
#include <math.h>

#define N_NODES 50000
#define N_EDGES 1600000
#define D_IN 128
#define D_H 64
#define N_CLS 10
#define N_GRAPHS 64
#define NEG_SLOPE 0.2f
#define E2 (N_EDGES + N_NODES)   // edges + self loops
#define SCAN_BS 256
#define NBLK ((N_NODES + SCAN_BS - 1) / SCAN_BS)   // 196 <= 256

// bucketed scatter params
#define NB 25                 // buckets: dst >> 11 (50000/2048 -> 0..24)
#define BSH 11
#define CAP 76800             // per-bucket staging capacity
#define CHUNKS (CAP / 256)    // 300 blocks per bucket in pass B
#define HBB 8                 // hist blocks per bucket

__device__ inline float wave_reduce_sum(float v) {
    for (int off = 32; off; off >>= 1) v += __shfl_xor(v, off);
    return v;
}

// one 8B load -> 4 floats from fp16 row chunk
__device__ inline float4 ld_h4(const __half* p) {
    int2 raw = *(const int2*)p;
    __half2 a = *(__half2*)&raw.x;
    __half2 b = *(__half2*)&raw.y;
    return make_float4(__low2float(a), __high2float(a), __low2float(b), __high2float(b));
}

// ===== pass A: bucket-stage edges + eattr sum. 2 edges/thread: halves the
// per-thread rank/store chain and doubles wave count vs 4/thread (scatter
// experiment R5/R6 showed chain-latency kernels want more, shorter waves).
__global__ void bucket_stage(const int* __restrict__ src, const int* __restrict__ dst,
                             const float* __restrict__ eattr,
                             float* esum, int* bcursor,
                             int4* __restrict__ stg) {
    __shared__ int bcnt[4][32];
    __shared__ int woff[4][32];
    int t = threadIdx.x;
    int wave = t >> 6;
    if (t < 128) bcnt[t >> 5][t & 31] = 0;
    __syncthreads();
    int e0 = (blockIdx.x * blockDim.x + t) * 2;   // N_EDGES % 2 == 0
    int2 s2, t2; float2 a2;
    int r[2], b[2];
    float v = 0.f;
    bool valid = e0 < N_EDGES;
    if (valid) {
        s2 = *(const int2*)(src + e0);
        t2 = *(const int2*)(dst + e0);
        a2 = *(const float2*)(eattr + e0);
        b[0] = t2.x >> BSH;
        b[1] = t2.y >> BSH;
        r[0] = atomicAdd(&bcnt[wave][b[0]], 1);
        r[1] = atomicAdd(&bcnt[wave][b[1]], 1);
        v = a2.x + a2.y;
    }
    v = wave_reduce_sum(v);
    if ((t & 63) == 0) atomicAdd(esum, v);
    __syncthreads();
    if (t < NB) {
        int c0 = bcnt[0][t], c1 = bcnt[1][t], c2 = bcnt[2][t], c3 = bcnt[3][t];
        int tot = c0 + c1 + c2 + c3;
        int base = tot ? atomicAdd(&bcursor[t], tot) : 0;
        woff[0][t] = base;
        woff[1][t] = base + c0;
        woff[2][t] = base + c0 + c1;
        woff[3][t] = base + c0 + c1 + c2;
    }
    __syncthreads();
    if (valid) {
        int p0 = b[0] * CAP + woff[wave][b[0]] + r[0];
        int p1 = b[1] * CAP + woff[wave][b[1]] + r[1];
        stg[p0] = make_int4(s2.x, __float_as_int(a2.x), t2.x, 0);
        stg[p1] = make_int4(s2.y, __float_as_int(a2.y), t2.y, 0);
    }
}

// ===== pass A2: per-node histogram from staged dst (.z), LDS-resident window
__global__ void hist_bucket(const int4* __restrict__ stg, const int* __restrict__ bcursor,
                            int* cnt) {
    __shared__ int hist[2048];
    int b = blockIdx.x / HBB;
    int j = blockIdx.x % HBB;
    for (int i = threadIdx.x; i < 2048; i += 256) hist[i] = 0;
    __syncthreads();
    int n = bcursor[b];
    const int4* sd = stg + b * CAP;
    int per = (n + HBB - 1) / HBB;
    int start = j * per;
    int end = min(start + per, n);
    for (int idx = start + threadIdx.x; idx < end; idx += 256)
        atomicAdd(&hist[sd[idx].z & 2047], 1);
    __syncthreads();
    int nb = b << BSH;
    for (int i = threadIdx.x; i < 2048; i += 256) {
        int c = hist[i];
        if (c) atomicAdd(&cnt[nb + i], c);
    }
}

// ---- block-local exclusive scan; +1 per node folds in the self-loop slot ----
__global__ void scan_block(const int* __restrict__ cnt, int* __restrict__ row_start,
                           int* __restrict__ partial) {
    __shared__ int sd[SCAN_BS];
    int i = blockIdx.x * SCAN_BS + threadIdx.x;
    int v = (i < N_NODES) ? (cnt[i] + 1) : 0;   // +1 = self loop
    sd[threadIdx.x] = v;
    __syncthreads();
    for (int off = 1; off < SCAN_BS; off <<= 1) {
        int t = (threadIdx.x >= off) ? sd[threadIdx.x - off] : 0;
        __syncthreads();
        sd[threadIdx.x] += t;
        __syncthreads();
    }
    if (i < N_NODES) row_start[i] = sd[threadIdx.x] - v;
    if (threadIdx.x == SCAN_BS - 1) partial[blockIdx.x] = sd[threadIdx.x];
}
// finalize row_start (redundant LDS scan of partials replaces a launch),
// write self-loop CSR entry, seed cursor
__global__ void add_offsets(int* __restrict__ row_start, const int* __restrict__ partial,
                            int* __restrict__ cursor, const float* __restrict__ esum,
                            int2* __restrict__ csr_pack) {
    __shared__ int sp[SCAN_BS];
    int pv = (threadIdx.x < NBLK) ? partial[threadIdx.x] : 0;
    sp[threadIdx.x] = pv;
    __syncthreads();
    for (int off = 1; off < SCAN_BS; off <<= 1) {
        int t = (threadIdx.x >= off) ? sp[threadIdx.x - off] : 0;
        __syncthreads();
        sp[threadIdx.x] += t;
        __syncthreads();
    }
    int base = (blockIdx.x == 0) ? 0 : sp[blockIdx.x - 1];
    int i = blockIdx.x * SCAN_BS + threadIdx.x;
    if (i < N_NODES) {
        int r = row_start[i] + base;
        row_start[i] = r;
        csr_pack[r] = make_int2(i, __float_as_int(esum[0] * (1.0f / N_EDGES)));
        cursor[i] = r + 1;
    }
    if (i == 0) row_start[N_NODES] = E2;
}

// ===== pass B: scatter within buckets (L2-confined windows, XCD swizzle)
__global__ void scatter_bucketed(const int4* __restrict__ stg,
                                 const int* __restrict__ bcursor, int* cursor,
                                 int2* __restrict__ csr_pack) {
    int g = blockIdx.x;
    int xcd = g & 7;
    int k = g >> 3;
    int b = xcd + 8 * (k / CHUNKS);
    if (b >= NB) return;
    int j = k % CHUNKS;
    int n = bcursor[b];
    int idx = j * 256 + threadIdx.x;
    if (idx >= n) return;
    int4 e = stg[b * CAP + idx];
    int q = atomicAdd(&cursor[e.z], 1);
    csr_pack[q] = make_int2(e.x, e.y);
}

// ---- xl = x@Wl + bl ; xr = x@Wr + br -> fp16 outputs (measured absmax 4.9e-4)
template<int K>
__global__ void linear_dual_k(const float* __restrict__ x,
                              const float* __restrict__ Wl, const float* __restrict__ bl,
                              const float* __restrict__ Wr, const float* __restrict__ br,
                              __half* __restrict__ xl, __half* __restrict__ xr) {
    const int NPW = 8;
    int wid = blockIdx.x * (blockDim.x >> 6) + (threadIdx.x >> 6);
    int d = threadIdx.x & 63;
    int n0 = wid * NPW;
    if (n0 >= N_NODES) return;
    float blv = bl[d], brv = br[d];
    float al[NPW], ar[NPW];
    #pragma unroll
    for (int i = 0; i < NPW; ++i) { al[i] = blv; ar[i] = brv; }
    const float4* xb = (const float4*)(x + (size_t)n0 * K);
    #pragma unroll 2
    for (int k4 = 0; k4 < K / 4; ++k4) {
        float4 xv[NPW];
        #pragma unroll
        for (int i = 0; i < NPW; ++i) xv[i] = xb[i * (K / 4) + k4];
        int kb = k4 * 4;
        float wl[4], wr[4];
        #pragma unroll
        for (int q = 0; q < 4; ++q) {
            wl[q] = Wl[(kb + q) * D_H + d];
            wr[q] = Wr[(kb + q) * D_H + d];
        }
        #pragma unroll
        for (int i = 0; i < NPW; ++i) {
            al[i] = fmaf(xv[i].x, wl[0], al[i]);
            al[i] = fmaf(xv[i].y, wl[1], al[i]);
            al[i] = fmaf(xv[i].z, wl[2], al[i]);
            al[i] = fmaf(xv[i].w, wl[3], al[i]);
            ar[i] = fmaf(xv[i].x, wr[0], ar[i]);
            ar[i] = fmaf(xv[i].y, wr[1], ar[i]);
            ar[i] = fmaf(xv[i].z, wr[2], ar[i]);
            ar[i] = fmaf(xv[i].w, wr[3], ar[i]);
        }
    }
    #pragma unroll
    for (int i = 0; i < NPW; ++i) {
        xl[(size_t)(n0 + i) * D_H + d] = __float2half(al[i]);
        xr[(size_t)(n0 + i) * D_H + d] = __float2half(ar[i]);
    }
}

// ---- fused GATv2 layer, 16-lane-group layout, 16 edges/iter, fp16 gathers.
// csr_pack fetched as 2x int4 (4 consecutive int2 entries) per iteration.
__global__ void gat_fused(const int* __restrict__ row_start, const int2* __restrict__ csr_pack,
                          const __half* __restrict__ xl, const __half* __restrict__ xr,
                          const float* __restrict__ We, const float* __restrict__ att,
                          const float* __restrict__ b, float* __restrict__ out) {
    int node = blockIdx.x * (blockDim.x >> 6) + (threadIdx.x >> 6);
    if (node >= N_NODES) return;
    int lane = threadIdx.x & 63;
    int g = lane >> 4;
    int s = lane & 15;
    int fb = s * 4;
    float4 we4  = *(const float4*)(We + fb);
    float4 att4 = *(const float4*)(att + fb);
    float4 xr4  = ld_h4(xr + (size_t)node * D_H + fb);
    int j0 = row_start[node], j1 = row_start[node + 1];

    float S = 0.f;
    float4 acc = make_float4(0.f, 0.f, 0.f, 0.f);

    for (int base = j0; base < j1; base += 16) {
        int i0 = base + 4 * g;
        bool v0 = i0 < j1, v1 = i0 + 1 < j1, v2 = i0 + 2 < j1, v3 = i0 + 3 < j1;
        int2 p0, p1, p2, p3;
        if (v3) {                      // whole quad in range: 2 vector loads
            int4 q01 = *(const int4*)(csr_pack + i0);
            int4 q23 = *(const int4*)(csr_pack + i0 + 2);
            p0 = make_int2(q01.x, q01.y); p1 = make_int2(q01.z, q01.w);
            p2 = make_int2(q23.x, q23.y); p3 = make_int2(q23.z, q23.w);
        } else {
            int c0 = v0 ? i0 : j0, c1 = v1 ? i0 + 1 : j0;
            int c2 = v2 ? i0 + 2 : j0, c3 = j0;
            p0 = csr_pack[c0]; p1 = csr_pack[c1]; p2 = csr_pack[c2]; p3 = csr_pack[c3];
        }
        float4 r0 = ld_h4(xl + (size_t)p0.x * D_H + fb);
        float4 r1 = ld_h4(xl + (size_t)p1.x * D_H + fb);
        float4 r2 = ld_h4(xl + (size_t)p2.x * D_H + fb);
        float4 r3 = ld_h4(xl + (size_t)p3.x * D_H + fb);
        float e0 = __int_as_float(p0.y), e1 = __int_as_float(p1.y);
        float e2 = __int_as_float(p2.y), e3 = __int_as_float(p3.y);

        float t0, t1, t2, t3;
        {
            float4 v;
            v.x = fmaf(e0, we4.x, r0.x + xr4.x); v.y = fmaf(e0, we4.y, r0.y + xr4.y);
            v.z = fmaf(e0, we4.z, r0.z + xr4.z); v.w = fmaf(e0, we4.w, r0.w + xr4.w);
            v.x = fmaxf(v.x, NEG_SLOPE * v.x); v.y = fmaxf(v.y, NEG_SLOPE * v.y);
            v.z = fmaxf(v.z, NEG_SLOPE * v.z); v.w = fmaxf(v.w, NEG_SLOPE * v.w);
            t0 = fmaf(v.w, att4.w, fmaf(v.z, att4.z, fmaf(v.y, att4.y, v.x * att4.x)));
            v.x = fmaf(e1, we4.x, r1.x + xr4.x); v.y = fmaf(e1, we4.y, r1.y + xr4.y);
            v.z = fmaf(e1, we4.z, r1.z + xr4.z); v.w = fmaf(e1, we4.w, r1.w + xr4.w);
            v.x = fmaxf(v.x, NEG_SLOPE * v.x); v.y = fmaxf(v.y, NEG_SLOPE * v.y);
            v.z = fmaxf(v.z, NEG_SLOPE * v.z); v.w = fmaxf(v.w, NEG_SLOPE * v.w);
            t1 = fmaf(v.w, att4.w, fmaf(v.z, att4.z, fmaf(v.y, att4.y, v.x * att4.x)));
            v.x = fmaf(e2, we4.x, r2.x + xr4.x); v.y = fmaf(e2, we4.y, r2.y + xr4.y);
            v.z = fmaf(e2, we4.z, r2.z + xr4.z); v.w = fmaf(e2, we4.w, r2.w + xr4.w);
            v.x = fmaxf(v.x, NEG_SLOPE * v.x); v.y = fmaxf(v.y, NEG_SLOPE * v.y);
            v.z = fmaxf(v.z, NEG_SLOPE * v.z); v.w = fmaxf(v.w, NEG_SLOPE * v.w);
            t2 = fmaf(v.w, att4.w, fmaf(v.z, att4.z, fmaf(v.y, att4.y, v.x * att4.x)));
            v.x = fmaf(e3, we4.x, r3.x + xr4.x); v.y = fmaf(e3, we4.y, r3.y + xr4.y);
            v.z = fmaf(e3, we4.z, r3.z + xr4.z); v.w = fmaf(e3, we4.w, r3.w + xr4.w);
            v.x = fmaxf(v.x, NEG_SLOPE * v.x); v.y = fmaxf(v.y, NEG_SLOPE * v.y);
            v.z = fmaxf(v.z, NEG_SLOPE * v.z); v.w = fmaxf(v.w, NEG_SLOPE * v.w);
            t3 = fmaf(v.w, att4.w, fmaf(v.z, att4.z, fmaf(v.y, att4.y, v.x * att4.x)));
        }
        #pragma unroll
        for (int off = 1; off <= 8; off <<= 1) {   // stays inside the 16-lane group
            t0 += __shfl_xor(t0, off);
            t1 += __shfl_xor(t1, off);
            t2 += __shfl_xor(t2, off);
            t3 += __shfl_xor(t3, off);
        }
        float z0 = v0 ? __expf(t0) : 0.f;
        float z1 = v1 ? __expf(t1) : 0.f;
        float z2 = v2 ? __expf(t2) : 0.f;
        float z3 = v3 ? __expf(t3) : 0.f;
        S += (z0 + z1) + (z2 + z3);
        acc.x = fmaf(z3, r3.x, fmaf(z2, r2.x, fmaf(z1, r1.x, fmaf(z0, r0.x, acc.x))));
        acc.y = fmaf(z3, r3.y, fmaf(z2, r2.y, fmaf(z1, r1.y, fmaf(z0, r0.y, acc.y))));
        acc.z = fmaf(z3, r3.z, fmaf(z2, r2.z, fmaf(z1, r1.z, fmaf(z0, r0.z, acc.z))));
        acc.w = fmaf(z3, r3.w, fmaf(z2, r2.w, fmaf(z1, r1.w, fmaf(z0, r0.w, acc.w))));
    }

    // plain sum-merge of the 4 groups (xor 16, then xor 32)
    #pragma unroll
    for (int off = 16; off <= 32; off <<= 1) {
        S     += __shfl_xor(S, off);
        acc.x += __shfl_xor(acc.x, off);
        acc.y += __shfl_xor(acc.y, off);
        acc.z += __shfl_xor(acc.z, off);
        acc.w += __shfl_xor(acc.w, off);
    }

    if (g == 0) {
        float4 b4 = *(const float4*)(b + fb);
        float inv = 1.f / (S + 1e-16f);
        float4 h;
        h.x = fmaf(acc.x, inv, b4.x);
        h.y = fmaf(acc.y, inv, b4.y);
        h.z = fmaf(acc.z, inv, b4.z);
        h.w = fmaf(acc.w, inv, b4.w);
        h.x = h.x > 0.f ? h.x : expm1f(h.x);
        h.y = h.y > 0.f ? h.y : expm1f(h.y);
        h.z = h.z > 0.f ? h.z : expm1f(h.z);
        h.w = h.w > 0.f ? h.w : expm1f(h.w);
        *(float4*)(out + (size_t)node * D_H + fb) = h;
    }
}

// ---- global mean pool (batch is sorted): register accumulate, flush on change
__global__ void pool(const float* __restrict__ h, const int* __restrict__ batch,
                     float* __restrict__ pooled, float* __restrict__ counts) {
    const int CHUNK = 128;
    int base = blockIdx.x * CHUNK;
    int d = threadIdx.x;  // blockDim = 64
    float accv = 0.f; int cur_g = -1; int cnt = 0;
    for (int i = 0; i < CHUNK; ++i) {
        int n = base + i;
        if (n >= N_NODES) break;
        int g = batch[n];
        if (g != cur_g) {
            if (cur_g >= 0) {
                atomicAdd(&pooled[cur_g * D_H + d], accv);
                if (d == 0) atomicAdd(&counts[cur_g], (float)cnt);
            }
            cur_g = g; accv = 0.f; cnt = 0;
        }
        accv += h[(size_t)n * D_H + d];
        cnt++;
    }
    if (cur_g >= 0) {
        atomicAdd(&pooled[cur_g * D_H + d], accv);
        if (d == 0) atomicAdd(&counts[cur_g], (float)cnt);
    }
}

__global__ void classify(const float* __restrict__ pooled, const float* __restrict__ counts,
                         const float* __restrict__ Wc, const float* __restrict__ bc,
                         float* __restrict__ out) {
    int tid = threadIdx.x;             // 640 threads
    int g = tid / N_CLS, c = tid % N_CLS;
    if (g >= N_GRAPHS) return;
    float inv = 1.0f / fmaxf(counts[g], 1.0f);
    float a = bc[c];
    for (int k = 0; k < D_H; ++k)
        a = fmaf(pooled[g * D_H + k] * inv, Wc[k * N_CLS + c], a);
    out[g * N_CLS + c] = a;
}

extern "C" void kernel_launch(void* const* d_in, const int* in_sizes, int n_in,
                              void* d_out, int out_size, void* d_ws, size_t ws_size,
                              hipStream_t stream) {
    const float* x     = (const float*)d_in[0];
    const int*   ei    = (const int*)d_in[1];
    const float* eattr = (const float*)d_in[2];
    const int*   batch = (const int*)d_in[3];
    const float *Wl1 = (const float*)d_in[4],  *bl1 = (const float*)d_in[5];
    const float *Wr1 = (const float*)d_in[6],  *br1 = (const float*)d_in[7];
    const float *We1 = (const float*)d_in[8],  *att1 = (const float*)d_in[9];
    const float *b1  = (const float*)d_in[10];
    const float *Wl2 = (const float*)d_in[11], *bl2 = (const float*)d_in[12];
    const float *Wr2 = (const float*)d_in[13], *br2 = (const float*)d_in[14];
    const float *We2 = (const float*)d_in[15], *att2 = (const float*)d_in[16];
    const float *b2  = (const float*)d_in[17];
    const float *Wc  = (const float*)d_in[18], *bc = (const float*)d_in[19];
    float* out = (float*)d_out;

    const int* src = ei;
    const int* dst = ei + N_EDGES;

    // workspace layout. stg (30.7 MB) is dead after scatter; xl/xr (fp16,
    // 6.4 MB each) + h (fp32, 12.8 MB) = 25.6 MB alias its region.
    char* base = (char*)d_ws;
    int4*  stg     = (int4*)base;                       // NB*CAP*16B = 30.72 MB
    __half* xl     = (__half*)base;                     // N*64 fp16 (6.4 MB)
    __half* xr     = xl + (size_t)N_NODES * D_H;        // N*64 fp16
    float* h       = (float*)(xr + (size_t)N_NODES * D_H); // N*64 fp32 (12.8 MB)
    int2*  csr_pack = (int2*)(base + (size_t)NB * CAP * 16); // E2 (8B) = 13.2 MB
    int*   row_start = (int*)(csr_pack + E2);           // N+1
    int*   cnt     = row_start + N_NODES + 1;           // N
    float* esum    = (float*)(cnt + N_NODES);           // 1
    int*   bcursor = (int*)(esum + 1);                  // NB   (memset with cnt)
    int*   cursor  = bcursor + NB;                      // N
    int*   partial = cursor + N_NODES;                  // NBLK
    float* pooled  = (float*)(partial + NBLK);          // 64*64
    float* counts  = pooled + N_GRAPHS * D_H;           // 64

    const int WPB = 4;  // waves per block at 256 threads
    int node_wave_blocks = (N_NODES + WPB - 1) / WPB;
    int lin_blocks = (N_NODES / 8 + WPB - 1) / WPB;

    hipMemsetAsync(cnt, 0, (N_NODES + 1 + NB) * sizeof(int), stream);   // cnt+esum+bcursor
    hipMemsetAsync(pooled, 0, (N_GRAPHS * D_H + N_GRAPHS) * sizeof(float), stream);

    // ---- CSR build: stage -> LDS hist -> scan -> scatter ----
    bucket_stage<<<(N_EDGES / 2 + 255) / 256, 256, 0, stream>>>(
        src, dst, eattr, esum, bcursor, stg);
    hist_bucket<<<NB * HBB, 256, 0, stream>>>(stg, bcursor, cnt);
    scan_block<<<NBLK, SCAN_BS, 0, stream>>>(cnt, row_start, partial);
    add_offsets<<<NBLK, SCAN_BS, 0, stream>>>(row_start, partial, cursor, esum, csr_pack);
    scatter_bucketed<<<8 * ((NB + 7) / 8) * CHUNKS, 256, 0, stream>>>(
        stg, bcursor, cursor, csr_pack);

    // ---------------- layer 1 ----------------
    linear_dual_k<D_IN><<<lin_blocks, 256, 0, stream>>>(x, Wl1, bl1, Wr1, br1, xl, xr);
    gat_fused<<<node_wave_blocks, 256, 0, stream>>>(row_start, csr_pack, xl, xr, We1, att1, b1, h);

    // ---------------- layer 2 ----------------
    linear_dual_k<D_H><<<lin_blocks, 256, 0, stream>>>(h, Wl2, bl2, Wr2, br2, xl, xr);
    gat_fused<<<node_wave_blocks, 256, 0, stream>>>(row_start, csr_pack, xl, xr, We2, att2, b2, h);

    // ---------------- pool + classify ----------------
    pool<<<(N_NODES + 127) / 128, 64, 0, stream>>>(h, batch, pooled, counts);
    classify<<<1, 640, 0, stream>>>(pooled, counts, Wc, bc, out);
}

// Round 16
// 575.049 us; speedup vs baseline: 1.1989x; 1.1989x over previous
//
#include <hip/hip_runtime.h>
#include <hip/hip_fp16.h>
#include <math.h>

#define N_NODES 50000
#define N_EDGES 1600000
#define D_IN 128
#define D_H 64
#define N_CLS 10
#define N_GRAPHS 64
#define NEG_SLOPE 0.2f
#define E2 (N_EDGES + N_NODES)   // edges + self loops
#define SCAN_BS 256
#define NBLK ((N_NODES + SCAN_BS - 1) / SCAN_BS)   // 196 <= 256

// bucketed scatter params
#define NB 25                 // buckets: dst >> 11 (50000/2048 -> 0..24)
#define BSH 11
#define CAP 76800             // per-bucket staging capacity
#define CHUNKS (CAP / 256)    // 300 blocks per bucket in pass B
#define HBB 8                 // hist blocks per bucket

__device__ inline float wave_reduce_sum(float v) {
    for (int off = 32; off; off >>= 1) v += __shfl_xor(v, off);
    return v;
}

// one 8B load -> 4 floats from fp16 row chunk
__device__ inline float4 ld_h4(const __half* p) {
    int2 raw = *(const int2*)p;
    __half2 a = *(__half2*)&raw.x;
    __half2 b = *(__half2*)&raw.y;
    return make_float4(__low2float(a), __high2float(a), __low2float(b), __high2float(b));
}

// ===== pass A: bucket-stage edges + eattr sum (int4 staging, per-wave counters)
// 4 edges/thread is the measured optimum (2/thr: 202us, 4/thr: 109us — more
// blocks multiply the bcursor-atomic & barrier coordination cost).
__global__ void bucket_stage(const int* __restrict__ src, const int* __restrict__ dst,
                             const float* __restrict__ eattr,
                             float* esum, int* bcursor,
                             int4* __restrict__ stg) {
    __shared__ int bcnt[4][32];
    __shared__ int woff[4][32];
    int t = threadIdx.x;
    int wave = t >> 6;
    if (t < 128) bcnt[t >> 5][t & 31] = 0;
    __syncthreads();
    int e0 = (blockIdx.x * blockDim.x + t) * 4;   // N_EDGES % 4 == 0
    int4 s4, t4; float4 a4;
    int r[4], b[4];
    float v = 0.f;
    bool valid = e0 < N_EDGES;
    if (valid) {
        s4 = *(const int4*)(src + e0);
        t4 = *(const int4*)(dst + e0);
        a4 = *(const float4*)(eattr + e0);
        int tt[4] = {t4.x, t4.y, t4.z, t4.w};
        #pragma unroll
        for (int i = 0; i < 4; ++i) {
            b[i] = tt[i] >> BSH;
            r[i] = atomicAdd(&bcnt[wave][b[i]], 1);
        }
        v = (a4.x + a4.y) + (a4.z + a4.w);
    }
    v = wave_reduce_sum(v);
    if ((t & 63) == 0) atomicAdd(esum, v);
    __syncthreads();
    if (t < NB) {
        int c0 = bcnt[0][t], c1 = bcnt[1][t], c2 = bcnt[2][t], c3 = bcnt[3][t];
        int tot = c0 + c1 + c2 + c3;
        int base = tot ? atomicAdd(&bcursor[t], tot) : 0;
        woff[0][t] = base;
        woff[1][t] = base + c0;
        woff[2][t] = base + c0 + c1;
        woff[3][t] = base + c0 + c1 + c2;
    }
    __syncthreads();
    if (valid) {
        int ss[4] = {s4.x, s4.y, s4.z, s4.w};
        int tt[4] = {t4.x, t4.y, t4.z, t4.w};
        int aa[4] = {__float_as_int(a4.x), __float_as_int(a4.y),
                     __float_as_int(a4.z), __float_as_int(a4.w)};
        #pragma unroll
        for (int i = 0; i < 4; ++i) {
            int p = b[i] * CAP + woff[wave][b[i]] + r[i];
            stg[p] = make_int4(ss[i], aa[i], tt[i], 0);
        }
    }
}

// ===== pass A2: per-node histogram from staged dst (.z), LDS-resident window
__global__ void hist_bucket(const int4* __restrict__ stg, const int* __restrict__ bcursor,
                            int* cnt) {
    __shared__ int hist[2048];
    int b = blockIdx.x / HBB;
    int j = blockIdx.x % HBB;
    for (int i = threadIdx.x; i < 2048; i += 256) hist[i] = 0;
    __syncthreads();
    int n = bcursor[b];
    const int4* sd = stg + b * CAP;
    int per = (n + HBB - 1) / HBB;
    int start = j * per;
    int end = min(start + per, n);
    for (int idx = start + threadIdx.x; idx < end; idx += 256)
        atomicAdd(&hist[sd[idx].z & 2047], 1);
    __syncthreads();
    int nb = b << BSH;
    for (int i = threadIdx.x; i < 2048; i += 256) {
        int c = hist[i];
        if (c) atomicAdd(&cnt[nb + i], c);
    }
}

// ---- block-local exclusive scan; +1 per node folds in the self-loop slot ----
__global__ void scan_block(const int* __restrict__ cnt, int* __restrict__ row_start,
                           int* __restrict__ partial) {
    __shared__ int sd[SCAN_BS];
    int i = blockIdx.x * SCAN_BS + threadIdx.x;
    int v = (i < N_NODES) ? (cnt[i] + 1) : 0;   // +1 = self loop
    sd[threadIdx.x] = v;
    __syncthreads();
    for (int off = 1; off < SCAN_BS; off <<= 1) {
        int t = (threadIdx.x >= off) ? sd[threadIdx.x - off] : 0;
        __syncthreads();
        sd[threadIdx.x] += t;
        __syncthreads();
    }
    if (i < N_NODES) row_start[i] = sd[threadIdx.x] - v;
    if (threadIdx.x == SCAN_BS - 1) partial[blockIdx.x] = sd[threadIdx.x];
}
// finalize row_start (redundant LDS scan of partials replaces a launch),
// write self-loop CSR entry, seed cursor
__global__ void add_offsets(int* __restrict__ row_start, const int* __restrict__ partial,
                            int* __restrict__ cursor, const float* __restrict__ esum,
                            int2* __restrict__ csr_pack) {
    __shared__ int sp[SCAN_BS];
    int pv = (threadIdx.x < NBLK) ? partial[threadIdx.x] : 0;
    sp[threadIdx.x] = pv;
    __syncthreads();
    for (int off = 1; off < SCAN_BS; off <<= 1) {
        int t = (threadIdx.x >= off) ? sp[threadIdx.x - off] : 0;
        __syncthreads();
        sp[threadIdx.x] += t;
        __syncthreads();
    }
    int base = (blockIdx.x == 0) ? 0 : sp[blockIdx.x - 1];
    int i = blockIdx.x * SCAN_BS + threadIdx.x;
    if (i < N_NODES) {
        int r = row_start[i] + base;
        row_start[i] = r;
        csr_pack[r] = make_int2(i, __float_as_int(esum[0] * (1.0f / N_EDGES)));
        cursor[i] = r + 1;
    }
    if (i == 0) row_start[N_NODES] = E2;
}

// ===== pass B: scatter within buckets (L2-confined windows, XCD swizzle)
__global__ void scatter_bucketed(const int4* __restrict__ stg,
                                 const int* __restrict__ bcursor, int* cursor,
                                 int2* __restrict__ csr_pack) {
    int g = blockIdx.x;
    int xcd = g & 7;
    int k = g >> 3;
    int b = xcd + 8 * (k / CHUNKS);
    if (b >= NB) return;
    int j = k % CHUNKS;
    int n = bcursor[b];
    int idx = j * 256 + threadIdx.x;
    if (idx >= n) return;
    int4 e = stg[b * CAP + idx];
    int q = atomicAdd(&cursor[e.z], 1);
    csr_pack[q] = make_int2(e.x, e.y);
}

// ---- xl = x@Wl + bl ; xr = x@Wr + br -> fp16 outputs (measured absmax 4.9e-4)
template<int K>
__global__ void linear_dual_k(const float* __restrict__ x,
                              const float* __restrict__ Wl, const float* __restrict__ bl,
                              const float* __restrict__ Wr, const float* __restrict__ br,
                              __half* __restrict__ xl, __half* __restrict__ xr) {
    const int NPW = 8;
    int wid = blockIdx.x * (blockDim.x >> 6) + (threadIdx.x >> 6);
    int d = threadIdx.x & 63;
    int n0 = wid * NPW;
    if (n0 >= N_NODES) return;
    float blv = bl[d], brv = br[d];
    float al[NPW], ar[NPW];
    #pragma unroll
    for (int i = 0; i < NPW; ++i) { al[i] = blv; ar[i] = brv; }
    const float4* xb = (const float4*)(x + (size_t)n0 * K);
    #pragma unroll 2
    for (int k4 = 0; k4 < K / 4; ++k4) {
        float4 xv[NPW];
        #pragma unroll
        for (int i = 0; i < NPW; ++i) xv[i] = xb[i * (K / 4) + k4];
        int kb = k4 * 4;
        float wl[4], wr[4];
        #pragma unroll
        for (int q = 0; q < 4; ++q) {
            wl[q] = Wl[(kb + q) * D_H + d];
            wr[q] = Wr[(kb + q) * D_H + d];
        }
        #pragma unroll
        for (int i = 0; i < NPW; ++i) {
            al[i] = fmaf(xv[i].x, wl[0], al[i]);
            al[i] = fmaf(xv[i].y, wl[1], al[i]);
            al[i] = fmaf(xv[i].z, wl[2], al[i]);
            al[i] = fmaf(xv[i].w, wl[3], al[i]);
            ar[i] = fmaf(xv[i].x, wr[0], ar[i]);
            ar[i] = fmaf(xv[i].y, wr[1], ar[i]);
            ar[i] = fmaf(xv[i].z, wr[2], ar[i]);
            ar[i] = fmaf(xv[i].w, wr[3], ar[i]);
        }
    }
    #pragma unroll
    for (int i = 0; i < NPW; ++i) {
        xl[(size_t)(n0 + i) * D_H + d] = __float2half(al[i]);
        xr[(size_t)(n0 + i) * D_H + d] = __float2half(ar[i]);
    }
}

// ---- fused GATv2 layer, 16-lane-group layout, 16 edges/iter, fp16 gathers.
// No running max (logits O(10), fp32 exp overflow at 88, shift-invariant).
__global__ void gat_fused(const int* __restrict__ row_start, const int2* __restrict__ csr_pack,
                          const __half* __restrict__ xl, const __half* __restrict__ xr,
                          const float* __restrict__ We, const float* __restrict__ att,
                          const float* __restrict__ b, float* __restrict__ out) {
    int node = blockIdx.x * (blockDim.x >> 6) + (threadIdx.x >> 6);
    if (node >= N_NODES) return;
    int lane = threadIdx.x & 63;
    int g = lane >> 4;
    int s = lane & 15;
    int fb = s * 4;
    float4 we4  = *(const float4*)(We + fb);
    float4 att4 = *(const float4*)(att + fb);
    float4 xr4  = ld_h4(xr + (size_t)node * D_H + fb);
    int j0 = row_start[node], j1 = row_start[node + 1];

    float S = 0.f;
    float4 acc = make_float4(0.f, 0.f, 0.f, 0.f);

    for (int base = j0; base < j1; base += 16) {
        int i0 = base + 4 * g;
        bool v0 = i0 < j1, v1 = i0 + 1 < j1, v2 = i0 + 2 < j1, v3 = i0 + 3 < j1;
        int c0 = v0 ? i0 : j0, c1 = v1 ? i0 + 1 : j0;
        int c2 = v2 ? i0 + 2 : j0, c3 = v3 ? i0 + 3 : j0;
        int2 p0 = csr_pack[c0], p1 = csr_pack[c1], p2 = csr_pack[c2], p3 = csr_pack[c3];
        float4 r0 = ld_h4(xl + (size_t)p0.x * D_H + fb);
        float4 r1 = ld_h4(xl + (size_t)p1.x * D_H + fb);
        float4 r2 = ld_h4(xl + (size_t)p2.x * D_H + fb);
        float4 r3 = ld_h4(xl + (size_t)p3.x * D_H + fb);
        float e0 = __int_as_float(p0.y), e1 = __int_as_float(p1.y);
        float e2 = __int_as_float(p2.y), e3 = __int_as_float(p3.y);

        float t0, t1, t2, t3;
        {
            float4 v;
            v.x = fmaf(e0, we4.x, r0.x + xr4.x); v.y = fmaf(e0, we4.y, r0.y + xr4.y);
            v.z = fmaf(e0, we4.z, r0.z + xr4.z); v.w = fmaf(e0, we4.w, r0.w + xr4.w);
            v.x = fmaxf(v.x, NEG_SLOPE * v.x); v.y = fmaxf(v.y, NEG_SLOPE * v.y);
            v.z = fmaxf(v.z, NEG_SLOPE * v.z); v.w = fmaxf(v.w, NEG_SLOPE * v.w);
            t0 = fmaf(v.w, att4.w, fmaf(v.z, att4.z, fmaf(v.y, att4.y, v.x * att4.x)));
            v.x = fmaf(e1, we4.x, r1.x + xr4.x); v.y = fmaf(e1, we4.y, r1.y + xr4.y);
            v.z = fmaf(e1, we4.z, r1.z + xr4.z); v.w = fmaf(e1, we4.w, r1.w + xr4.w);
            v.x = fmaxf(v.x, NEG_SLOPE * v.x); v.y = fmaxf(v.y, NEG_SLOPE * v.y);
            v.z = fmaxf(v.z, NEG_SLOPE * v.z); v.w = fmaxf(v.w, NEG_SLOPE * v.w);
            t1 = fmaf(v.w, att4.w, fmaf(v.z, att4.z, fmaf(v.y, att4.y, v.x * att4.x)));
            v.x = fmaf(e2, we4.x, r2.x + xr4.x); v.y = fmaf(e2, we4.y, r2.y + xr4.y);
            v.z = fmaf(e2, we4.z, r2.z + xr4.z); v.w = fmaf(e2, we4.w, r2.w + xr4.w);
            v.x = fmaxf(v.x, NEG_SLOPE * v.x); v.y = fmaxf(v.y, NEG_SLOPE * v.y);
            v.z = fmaxf(v.z, NEG_SLOPE * v.z); v.w = fmaxf(v.w, NEG_SLOPE * v.w);
            t2 = fmaf(v.w, att4.w, fmaf(v.z, att4.z, fmaf(v.y, att4.y, v.x * att4.x)));
            v.x = fmaf(e3, we4.x, r3.x + xr4.x); v.y = fmaf(e3, we4.y, r3.y + xr4.y);
            v.z = fmaf(e3, we4.z, r3.z + xr4.z); v.w = fmaf(e3, we4.w, r3.w + xr4.w);
            v.x = fmaxf(v.x, NEG_SLOPE * v.x); v.y = fmaxf(v.y, NEG_SLOPE * v.y);
            v.z = fmaxf(v.z, NEG_SLOPE * v.z); v.w = fmaxf(v.w, NEG_SLOPE * v.w);
            t3 = fmaf(v.w, att4.w, fmaf(v.z, att4.z, fmaf(v.y, att4.y, v.x * att4.x)));
        }
        #pragma unroll
        for (int off = 1; off <= 8; off <<= 1) {   // stays inside the 16-lane group
            t0 += __shfl_xor(t0, off);
            t1 += __shfl_xor(t1, off);
            t2 += __shfl_xor(t2, off);
            t3 += __shfl_xor(t3, off);
        }
        float z0 = v0 ? __expf(t0) : 0.f;
        float z1 = v1 ? __expf(t1) : 0.f;
        float z2 = v2 ? __expf(t2) : 0.f;
        float z3 = v3 ? __expf(t3) : 0.f;
        S += (z0 + z1) + (z2 + z3);
        acc.x = fmaf(z3, r3.x, fmaf(z2, r2.x, fmaf(z1, r1.x, fmaf(z0, r0.x, acc.x))));
        acc.y = fmaf(z3, r3.y, fmaf(z2, r2.y, fmaf(z1, r1.y, fmaf(z0, r0.y, acc.y))));
        acc.z = fmaf(z3, r3.z, fmaf(z2, r2.z, fmaf(z1, r1.z, fmaf(z0, r0.z, acc.z))));
        acc.w = fmaf(z3, r3.w, fmaf(z2, r2.w, fmaf(z1, r1.w, fmaf(z0, r0.w, acc.w))));
    }

    // plain sum-merge of the 4 groups (xor 16, then xor 32)
    #pragma unroll
    for (int off = 16; off <= 32; off <<= 1) {
        S     += __shfl_xor(S, off);
        acc.x += __shfl_xor(acc.x, off);
        acc.y += __shfl_xor(acc.y, off);
        acc.z += __shfl_xor(acc.z, off);
        acc.w += __shfl_xor(acc.w, off);
    }

    if (g == 0) {
        float4 b4 = *(const float4*)(b + fb);
        float inv = 1.f / (S + 1e-16f);
        float4 h;
        h.x = fmaf(acc.x, inv, b4.x);
        h.y = fmaf(acc.y, inv, b4.y);
        h.z = fmaf(acc.z, inv, b4.z);
        h.w = fmaf(acc.w, inv, b4.w);
        h.x = h.x > 0.f ? h.x : expm1f(h.x);
        h.y = h.y > 0.f ? h.y : expm1f(h.y);
        h.z = h.z > 0.f ? h.z : expm1f(h.z);
        h.w = h.w > 0.f ? h.w : expm1f(h.w);
        *(float4*)(out + (size_t)node * D_H + fb) = h;
    }
}

// ---- global mean pool (batch is sorted): register accumulate, flush on change
__global__ void pool(const float* __restrict__ h, const int* __restrict__ batch,
                     float* __restrict__ pooled, float* __restrict__ counts) {
    const int CHUNK = 128;
    int base = blockIdx.x * CHUNK;
    int d = threadIdx.x;  // blockDim = 64
    float accv = 0.f; int cur_g = -1; int cnt = 0;
    for (int i = 0; i < CHUNK; ++i) {
        int n = base + i;
        if (n >= N_NODES) break;
        int g = batch[n];
        if (g != cur_g) {
            if (cur_g >= 0) {
                atomicAdd(&pooled[cur_g * D_H + d], accv);
                if (d == 0) atomicAdd(&counts[cur_g], (float)cnt);
            }
            cur_g = g; accv = 0.f; cnt = 0;
        }
        accv += h[(size_t)n * D_H + d];
        cnt++;
    }
    if (cur_g >= 0) {
        atomicAdd(&pooled[cur_g * D_H + d], accv);
        if (d == 0) atomicAdd(&counts[cur_g], (float)cnt);
    }
}

__global__ void classify(const float* __restrict__ pooled, const float* __restrict__ counts,
                         const float* __restrict__ Wc, const float* __restrict__ bc,
                         float* __restrict__ out) {
    int tid = threadIdx.x;             // 640 threads
    int g = tid / N_CLS, c = tid % N_CLS;
    if (g >= N_GRAPHS) return;
    float inv = 1.0f / fmaxf(counts[g], 1.0f);
    float a = bc[c];
    for (int k = 0; k < D_H; ++k)
        a = fmaf(pooled[g * D_H + k] * inv, Wc[k * N_CLS + c], a);
    out[g * N_CLS + c] = a;
}

extern "C" void kernel_launch(void* const* d_in, const int* in_sizes, int n_in,
                              void* d_out, int out_size, void* d_ws, size_t ws_size,
                              hipStream_t stream) {
    const float* x     = (const float*)d_in[0];
    const int*   ei    = (const int*)d_in[1];
    const float* eattr = (const float*)d_in[2];
    const int*   batch = (const int*)d_in[3];
    const float *Wl1 = (const float*)d_in[4],  *bl1 = (const float*)d_in[5];
    const float *Wr1 = (const float*)d_in[6],  *br1 = (const float*)d_in[7];
    const float *We1 = (const float*)d_in[8],  *att1 = (const float*)d_in[9];
    const float *b1  = (const float*)d_in[10];
    const float *Wl2 = (const float*)d_in[11], *bl2 = (const float*)d_in[12];
    const float *Wr2 = (const float*)d_in[13], *br2 = (const float*)d_in[14];
    const float *We2 = (const float*)d_in[15], *att2 = (const float*)d_in[16];
    const float *b2  = (const float*)d_in[17];
    const float *Wc  = (const float*)d_in[18], *bc = (const float*)d_in[19];
    float* out = (float*)d_out;

    const int* src = ei;
    const int* dst = ei + N_EDGES;

    // workspace layout. stg (30.7 MB) is dead after scatter; xl/xr (fp16,
    // 6.4 MB each) + h (fp32, 12.8 MB) = 25.6 MB alias its region.
    char* base = (char*)d_ws;
    int4*  stg     = (int4*)base;                       // NB*CAP*16B = 30.72 MB
    __half* xl     = (__half*)base;                     // N*64 fp16 (6.4 MB)
    __half* xr     = xl + (size_t)N_NODES * D_H;        // N*64 fp16
    float* h       = (float*)(xr + (size_t)N_NODES * D_H); // N*64 fp32 (12.8 MB)
    int2*  csr_pack = (int2*)(base + (size_t)NB * CAP * 16); // E2 (8B) = 13.2 MB
    int*   row_start = (int*)(csr_pack + E2);           // N+1
    int*   cnt     = row_start + N_NODES + 1;           // N
    float* esum    = (float*)(cnt + N_NODES);           // 1
    int*   bcursor = (int*)(esum + 1);                  // NB   (memset with cnt)
    int*   cursor  = bcursor + NB;                      // N
    int*   partial = cursor + N_NODES;                  // NBLK
    float* pooled  = (float*)(partial + NBLK);          // 64*64
    float* counts  = pooled + N_GRAPHS * D_H;           // 64

    const int WPB = 4;  // waves per block at 256 threads
    int node_wave_blocks = (N_NODES + WPB - 1) / WPB;
    int lin_blocks = (N_NODES / 8 + WPB - 1) / WPB;

    hipMemsetAsync(cnt, 0, (N_NODES + 1 + NB) * sizeof(int), stream);   // cnt+esum+bcursor
    hipMemsetAsync(pooled, 0, (N_GRAPHS * D_H + N_GRAPHS) * sizeof(float), stream);

    // ---- CSR build: stage -> LDS hist -> scan -> scatter ----
    bucket_stage<<<(N_EDGES / 4 + 255) / 256, 256, 0, stream>>>(
        src, dst, eattr, esum, bcursor, stg);
    hist_bucket<<<NB * HBB, 256, 0, stream>>>(stg, bcursor, cnt);
    scan_block<<<NBLK, SCAN_BS, 0, stream>>>(cnt, row_start, partial);
    add_offsets<<<NBLK, SCAN_BS, 0, stream>>>(row_start, partial, cursor, esum, csr_pack);
    scatter_bucketed<<<8 * ((NB + 7) / 8) * CHUNKS, 256, 0, stream>>>(
        stg, bcursor, cursor, csr_pack);

    // ---------------- layer 1 ----------------
    linear_dual_k<D_IN><<<lin_blocks, 256, 0, stream>>>(x, Wl1, bl1, Wr1, br1, xl, xr);
    gat_fused<<<node_wave_blocks, 256, 0, stream>>>(row_start, csr_pack, xl, xr, We1, att1, b1, h);

    // ---------------- layer 2 ----------------
    linear_dual_k<D_H><<<lin_blocks, 256, 0, stream>>>(h, Wl2, bl2, Wr2, br2, xl, xr);
    gat_fused<<<node_wave_blocks, 256, 0, stream>>>(row_start, csr_pack, xl, xr, We2, att2, b2, h);

    // ---------------- pool + classify ----------------
    pool<<<(N_NODES + 127) / 128, 64, 0, stream>>>(h, batch, pooled, counts);
    classify<<<1, 640, 0, stream>>>(pooled, counts, Wc, bc, out);
}